// Round 1
// 196.984 us; speedup vs baseline: 1.0368x; 1.0368x over previous
//
#include <hip/hip_runtime.h>
#include <hip/hip_bf16.h>

// Problem: B=256, T=256, C=384, H=64, MAX_REL=3 (causal -> rel idx 0..3 only)
// Round 8: FUSION. r7 ran three kernels with q/k/vT round-tripping through
// global memory and attention at 1 wave/block pulling k/vT through L2.
// Mandatory HBM traffic is only x (100 MB) + out (17 MB) ~= 19 us; the rest
// was structural. New shape:
//   - grid 256 = one block per batch = exactly 1 block/CU, 8 waves, 156 KB LDS.
//   - Phase 1 (QKV): W staged in 3 x 48 KB LDS chunks; each wave owns 32 rows
//     (2 row-tiles sharing every W B-fragment -> 0.5 ds_read per MFMA);
//     q/k/vT written to LDS ONLY -- never to HBM.
//   - Phase 2 (attn): wave w handles q-tiles {w, 15-w} = 17 s-tiles each
//     (perfect causal balance; PV ksteps = 9 for every wave). k/vT/P all in
//     LDS; per-wave P buffer reuses the LDS freed by q/W after one barrier.
//   - All r4/r6-verified MFMA fragment patterns + numerics kept verbatim.

typedef __attribute__((ext_vector_type(8))) __bf16 bf16x8;
typedef __attribute__((ext_vector_type(8))) short short8;
typedef __attribute__((ext_vector_type(4))) float f32x4;
typedef __attribute__((ext_vector_type(4))) int   i32x4;

#define MFMA16(A, B, C) __builtin_amdgcn_mfma_f32_16x16x32_bf16((A), (B), (C), 0, 0, 0)

__device__ __forceinline__ unsigned short f2bf(float f) {
    unsigned int u = __builtin_bit_cast(unsigned int, f);
    u = (u + 0x7FFFu + ((u >> 16) & 1u)) >> 16;   // RNE
    return (unsigned short)u;
}
__device__ __forceinline__ float bf2f(unsigned short s) {
    unsigned int u = ((unsigned int)s) << 16;
    return __builtin_bit_cast(float, u);
}
__device__ __forceinline__ bf16x8 ld16(const unsigned short* p) {
    return __builtin_bit_cast(bf16x8, *(const i32x4*)p);
}

// ---------------------------------------------------------------------------
// Kernel 0: Wt[3][64][384] bf16 (W^T) + Rk[16][64] bf16 (rel_k rows 0..3, rest 0)
// ---------------------------------------------------------------------------
__global__ void prep_wt(const float* __restrict__ Wq, const float* __restrict__ Wk,
                        const float* __restrict__ Wv, const float* __restrict__ relk,
                        unsigned short* __restrict__ Wt, unsigned short* __restrict__ Rk) {
    int i = blockIdx.x * 256 + threadIdx.x;
    if (i < 3 * 64 * 384) {
        int kk = i % 384;
        int h  = (i / 384) & 63;
        int w  = i / (384 * 64);
        const float* W = (w == 0) ? Wq : ((w == 1) ? Wk : Wv);
        Wt[i] = f2bf(W[kk * 64 + h]);
    } else if (i < 3 * 64 * 384 + 1024) {
        int j = i - 3 * 64 * 384;
        int n = j >> 6, h = j & 63;
        Rk[j] = (n < 4) ? f2bf(relk[n * 64 + h]) : (unsigned short)0;
    }
}

// ---------------------------------------------------------------------------
// Fused QKV + attention. One block per batch, 512 threads (8 waves).
// LDS layout (u16 offsets; total 79872 u16 = 159744 B):
//   ksh [256][72]  @ 0       36864 B   persistent
//   vTs [64][264]  @ 18432   33792 B   persistent
//   qs  [256][72]  @ 35328   36864 B   freed after phase 2a  \  P region
//   wc  [192][136] @ 53760   52224 B   freed after phase 1   /  (8 x 8448 B)
//   Pw(wave w) = 35328 + w*4224, [16][264]
// All row strides (72/136/264 u16) are 4*dword+32k -> 2-way bank aliasing
// (free) on the 16-lane b128 column reads.
// ---------------------------------------------------------------------------
__global__ __launch_bounds__(512, 1) void fused_kernel(
        const float* __restrict__ x, const unsigned short* __restrict__ Wt,
        const unsigned short* __restrict__ Rk, const float* __restrict__ relv,
        float* __restrict__ out) {
    extern __shared__ unsigned short sh[];
    unsigned short* ksh = sh;
    unsigned short* vTs = sh + 18432;
    unsigned short* qs  = sh + 35328;
    unsigned short* wc  = sh + 53760;

    const int tid  = threadIdx.x;
    const int wave = tid >> 6;
    const int lane = tid & 63;
    const int c    = lane & 15;
    const int quad = lane >> 4;
    const int b    = blockIdx.x;

    const f32x4 zero = {0.f, 0.f, 0.f, 0.f};

    // =================== phase 1: QKV GEMM into LDS ===================
    const float* xbase = x + (size_t)(b * 256 + wave * 32 + c) * 384 + quad * 8;

    f32x4 aq[2][4], ak[2][4], av[2][4];
#pragma unroll
    for (int rt = 0; rt < 2; rt++)
#pragma unroll
        for (int nt = 0; nt < 4; nt++) { aq[rt][nt] = zero; ak[rt][nt] = zero; av[rt][nt] = zero; }

    // prologue: issue x loads for chunk 0 (16 KB/wave in flight -> HBM saturating)
    f32x4 tmp[2][8];
#pragma unroll
    for (int rt = 0; rt < 2; rt++)
#pragma unroll
        for (int j = 0; j < 4; j++) {
            const float* xp = xbase + rt * 6144 + j * 32;
            tmp[rt][2 * j]     = *(const f32x4*)xp;
            tmp[rt][2 * j + 1] = *(const f32x4*)(xp + 4);
        }

#pragma unroll
    for (int ck = 0; ck < 3; ck++) {
        if (ck) __syncthreads();               // all waves done reading wc(ck-1)
        // stage W chunk ck: 192 rows x 128 u16, 6 b128 pieces per thread (L2-hot)
#pragma unroll
        for (int it = 0; it < 6; it++) {
            int P_ = it * 512 + tid;
            int r = P_ >> 4, pc = P_ & 15;
            i32x4 d = *(const i32x4*)(Wt + r * 384 + ck * 128 + pc * 8);
            *(i32x4*)(wc + r * 136 + pc * 8) = d;
        }
        __syncthreads();                       // wc ready; also drains x loads

        // convert this chunk's x to bf16 A-frags (frees tmp for the prefetch)
        bf16x8 a[2][4];
#pragma unroll
        for (int rt = 0; rt < 2; rt++)
#pragma unroll
            for (int j = 0; j < 4; j++) {
                short8 xs8;
#pragma unroll
                for (int e = 0; e < 4; e++) {
                    xs8[e]     = (short)f2bf(tmp[rt][2 * j][e]);
                    xs8[4 + e] = (short)f2bf(tmp[rt][2 * j + 1][e]);
                }
                a[rt][j] = __builtin_bit_cast(bf16x8, xs8);
            }
        // prefetch next chunk's x; lands during the MFMA loop below
        if (ck < 2) {
#pragma unroll
            for (int rt = 0; rt < 2; rt++)
#pragma unroll
                for (int j = 0; j < 4; j++) {
                    const float* xp = xbase + rt * 6144 + (ck + 1) * 128 + j * 32;
                    tmp[rt][2 * j]     = *(const f32x4*)xp;
                    tmp[rt][2 * j + 1] = *(const f32x4*)(xp + 4);
                }
        }

        // 3 B-frag loads feed 6 MFMAs (both row-tiles share W fragments)
#pragma unroll
        for (int j = 0; j < 4; j++) {
            const int col = j * 32 + quad * 8;
#pragma unroll
            for (int nt = 0; nt < 4; nt++) {
                bf16x8 bq = ld16(wc + (nt * 16 + c) * 136 + col);
                bf16x8 bk = ld16(wc + (64 + nt * 16 + c) * 136 + col);
                bf16x8 aw = ld16(wc + (128 + nt * 16 + c) * 136 + col);
                aq[0][nt] = MFMA16(a[0][j], bq, aq[0][nt]);   // D[t][h]
                aq[1][nt] = MFMA16(a[1][j], bq, aq[1][nt]);
                ak[0][nt] = MFMA16(a[0][j], bk, ak[0][nt]);
                ak[1][nt] = MFMA16(a[1][j], bk, ak[1][nt]);
                av[0][nt] = MFMA16(aw, a[0][j], av[0][nt]);   // D[h][t]
                av[1][nt] = MFMA16(aw, a[1][j], av[1][nt]);
            }
        }
    }

    // epilogue into LDS (C/D layout: col=lane&15, row=quad*4+reg)
#pragma unroll
    for (int rt = 0; rt < 2; rt++)
#pragma unroll
        for (int nt = 0; nt < 4; nt++)
#pragma unroll
            for (int r = 0; r < 4; r++) {
                int row = wave * 32 + rt * 16 + quad * 4 + r;
                qs[row * 72 + nt * 16 + c]  = f2bf(aq[rt][nt][r]);
                ksh[row * 72 + nt * 16 + c] = f2bf(ak[rt][nt][r]);
                vTs[(nt * 16 + quad * 4 + r) * 264 + wave * 32 + rt * 16 + c] = f2bf(av[rt][nt][r]);
            }
    __syncthreads();                           // q/k/vT visible to all waves

    // =================== phase 2: attention from LDS ===================
    const int tA = wave, tB = 15 - wave;       // 17 s-tiles per wave, balanced
    bf16x8 qA0 = ld16(qs + (tA * 16 + c) * 72 + quad * 8);
    bf16x8 qA1 = ld16(qs + (tA * 16 + c) * 72 + 32 + quad * 8);
    bf16x8 qB0 = ld16(qs + (tB * 16 + c) * 72 + quad * 8);
    bf16x8 qB1 = ld16(qs + (tB * 16 + c) * 72 + 32 + quad * 8);
    float rv[4][4];
#pragma unroll
    for (int j = 0; j < 4; j++)
#pragma unroll
        for (int nt = 0; nt < 4; nt++) rv[j][nt] = relv[j * 64 + nt * 16 + c];
    __syncthreads();                           // qs reads done -> P may overwrite

    unsigned short* Pw = sh + 35328 + wave * 4224;   // per-wave [16][264]

#pragma unroll
    for (int it2 = 0; it2 < 2; it2++) {
        const int tt  = it2 ? tB : tA;
        const bf16x8 aq0 = it2 ? qB0 : qA0;
        const bf16x8 aq1 = it2 ? qB1 : qA1;
        const int nst = tt + 1;

        // E via MFMA vs Rk: D[m=quad*4+r][n=c] = q_{t0+m} . relk_n  (n<4 valid)
        f32x4 e = zero;
        e = MFMA16(aq0, ld16(Rk + c * 64 + quad * 8), e);
        e = MFMA16(aq1, ld16(Rk + c * 64 + 32 + quad * 8), e);
        float ef[4][4];
#pragma unroll
        for (int r = 0; r < 4; r++)
#pragma unroll
            for (int n = 0; n < 4; n++)
                ef[r][n] = __shfl(e[r], (lane & 48) + n, 64);

        // previous tile's P reads must retire before overwriting (wave-local)
        __asm__ __volatile__("s_waitcnt lgkmcnt(0)" ::: "memory");

        // score tiles -> exp -> P^ in LDS; accumulate row sums
        float l[4] = {0.f, 0.f, 0.f, 0.f};
#pragma unroll
        for (int st = 0; st < 16; st++) {
            if (st < nst) {
                const unsigned short* kp = ksh + (st * 16 + c) * 72 + quad * 8;
                f32x4 s = zero;
                s = MFMA16(aq0, ld16(kp), s);
                s = MFMA16(aq1, ld16(kp + 32), s);
#pragma unroll
                for (int r = 0; r < 4; r++) {
                    int tg = tt * 16 + quad * 4 + r;
                    int sg = st * 16 + c;
                    int d  = sg - tg;
                    float ee = (d <= -3) ? ef[r][0] : (d == -2) ? ef[r][1]
                             : (d == -1) ? ef[r][2] : ef[r][3];
                    float p = (d > 0) ? 0.f : __expf(0.125f * (s[r] + ee));
                    l[r] += p;
                    Pw[(quad * 4 + r) * 264 + sg] = f2bf(p);
                }
            }
        }
        if (nst & 1) {                         // zero-pad half-open MFMA k-tile
#pragma unroll
            for (int r = 0; r < 4; r++) Pw[(quad * 4 + r) * 264 + nst * 16 + c] = 0;
        }
#pragma unroll
        for (int r = 0; r < 4; r++)
#pragma unroll
            for (int ofs = 1; ofs < 16; ofs <<= 1)
                l[r] += __shfl_xor(l[r], ofs, 64);
        float rl[4];
#pragma unroll
        for (int r = 0; r < 4; r++) rl[r] = 1.0f / l[r];

        __asm__ __volatile__("s_waitcnt lgkmcnt(0)" ::: "memory");  // P^ visible

        // O = P^ @ V  (A rows m=c from P; B = vT rows from LDS)
        f32x4 o[4];
#pragma unroll
        for (int nt = 0; nt < 4; nt++) o[nt] = zero;
        const int ksteps = (nst + 1) >> 1;
#pragma unroll
        for (int ks = 0; ks < 8; ks++) {
            if (ks < ksteps) {
                bf16x8 ap = ld16(Pw + c * 264 + ks * 32 + quad * 8);
#pragma unroll
                for (int nt = 0; nt < 4; nt++) {
                    bf16x8 bv = ld16(vTs + (nt * 16 + c) * 264 + ks * 32 + quad * 8);
                    o[nt] = MFMA16(ap, bv, o[nt]);
                }
            }
        }

        // epilogue: normalize + w2 band-probability identity + store
#pragma unroll
        for (int r = 0; r < 4; r++) {
            int tl = quad * 4 + r;
            int tg = tt * 16 + tl;
            float pa  = (tg >= 2) ? bf2f(Pw[tl * 264 + tg - 2]) * rl[r] : 0.f;
            float pb  = (tg >= 1) ? bf2f(Pw[tl * 264 + tg - 1]) * rl[r] : 0.f;
            float pcv = bf2f(Pw[tl * 264 + tg]) * rl[r];
#pragma unroll
            for (int nt = 0; nt < 4; nt++) {
                float r0 = rv[0][nt];
                float w2 = r0 + pa * (rv[1][nt] - r0) + pb * (rv[2][nt] - r0)
                              + pcv * (rv[3][nt] - r0);
                out[(size_t)(b * 256 + tg) * 64 + nt * 16 + c] = o[nt][r] * rl[r] + w2;
            }
        }
    }
}

// ---------------------------------------------------------------------------
extern "C" void kernel_launch(void* const* d_in, const int* in_sizes, int n_in,
                              void* d_out, int out_size, void* d_ws, size_t ws_size,
                              hipStream_t stream) {
    const float* x    = (const float*)d_in[0];
    const float* Wq   = (const float*)d_in[1];
    const float* Wk   = (const float*)d_in[2];
    const float* Wv   = (const float*)d_in[3];
    const float* relk = (const float*)d_in[4];
    const float* relv = (const float*)d_in[5];
    float* out = (float*)d_out;

    char* ws = (char*)d_ws;
    unsigned short* Wt = (unsigned short*)(ws);              // 147456 B
    unsigned short* Rk = (unsigned short*)(ws + 147456);     // 2048 B

    (void)hipFuncSetAttribute((const void*)fused_kernel,
                              hipFuncAttributeMaxDynamicSharedMemorySize, 159744);

    prep_wt<<<292, 256, 0, stream>>>(Wq, Wk, Wv, relk, Wt, Rk);
    fused_kernel<<<256, 512, 159744, stream>>>(x, Wt, Rk, relv, out);
}